// Round 2
// baseline (1054.074 us; speedup 1.0000x reference)
//
#include <hip/hip_runtime.h>
#include <cstddef>

// z: (8, 256, 16,16,16) fp32; embedding: (1024, 256) fp32
#define CDIM 256
#define SPAT 4096            // 16*16*16
#define KCODE 1024

#define LOSS_OFF 8388608
#define PERP_OFF 8388609
#define IDX_OFF  8388610

// ---------------------------------------------------------------------------
// Fused: distance GEMM + argmin + gather + loss partials + counts + e-norms
// grid 512 blocks (64 columns each) x 256 threads, 2 blocks/CU (81920 B LDS)
// thread tile: 16 codes x 8 cols; k-tiles of 512 codes (2 tiles)
// LDS: zt[256][64] persists z-tile; et[8][512] stages e-chunks (XOR-swizzled)
//      zz / e-norm exchange / argmin reduction / bidx all overlay inside et.
// ---------------------------------------------------------------------------
__global__ __launch_bounds__(256, 2) void vq_main(const float* __restrict__ z,
                                                  const float* __restrict__ emb,
                                                  float* __restrict__ counts,
                                                  float* __restrict__ losssum,
                                                  float* __restrict__ out) {
    __shared__ float zt[CDIM * 64];   // 64 KB, [c][col]
    __shared__ float et[8 * 512];     // 16 KB, [cc][kk] swizzled (+ overlays)

    const int tid = threadIdx.x;
    const int n0 = blockIdx.x * 64;        // first global column
    const int b = n0 >> 12;                // batch (4096 cols per batch)
    const int sp0 = n0 & 4095;
    const float* zb = z + (size_t)b * CDIM * SPAT + sp0;

    // ---- stage z-tile (coalesced: 16 lanes x float4 = 256B per c-row) ----
    for (int i = tid; i < CDIM * 16; i += 256) {
        int c = i >> 4, seg = i & 15;
        float4 v = *(const float4*)(zb + (size_t)c * SPAT + seg * 4);
        *(float4*)&zt[c * 64 + seg * 4] = v;
    }
    __syncthreads();

    // ---- zz per column: order identical to the R1-passing kernel ----
    if (tid < 64) {
        float s = 0.0f;
        for (int c = 0; c < CDIM; ++c) {
            float v = zt[c * 64 + tid];
            s = fmaf(v, v, s);
        }
        et[tid] = s;   // overlay: zz lives in et[0..64)
    }
    __syncthreads();

    const int cx = tid & 7;   // column group: cols 8*cx .. 8*cx+7
    const int ky = tid >> 3;  // code group within 512-tile: codes 16*ky ..

    float zzv[8];
    {
        float4 a = *(const float4*)&et[cx * 8];
        float4 c = *(const float4*)&et[cx * 8 + 4];
        zzv[0] = a.x; zzv[1] = a.y; zzv[2] = a.z; zzv[3] = a.w;
        zzv[4] = c.x; zzv[5] = c.y; zzv[6] = c.z; zzv[7] = c.w;
    }
    __syncthreads();   // done with zz overlay before et staging

    // XOR swizzle: phys(kk) = kk ^ ((kk>>5)<<2) — kills the 4-way bank
    // conflict of stride-16 reads while keeping 16B-aligned contiguous b128s.
    const int ph0 = tid ^ ((tid >> 5) << 2);
    const int kk1 = tid + 256;
    const int ph1 = kk1 ^ ((kk1 >> 5) << 2);
    const int cst = (ky >> 1) << 2;
    const int rb0 = (ky * 16 + 0) ^ cst;
    const int rb1 = (ky * 16 + 4) ^ cst;
    const int rb2 = (ky * 16 + 8) ^ cst;
    const int rb3 = (ky * 16 + 12) ^ cst;

    float bs[8];
    int   bi[8];
#pragma unroll
    for (int j = 0; j < 8; ++j) { bs[j] = 3.4e38f; bi[j] = 0; }

    for (int t = 0; t < 2; ++t) {
        const int k0 = t * 512;
        float acc[16][8];
#pragma unroll
        for (int i = 0; i < 16; ++i)
#pragma unroll
            for (int j = 0; j < 8; ++j) acc[i][j] = 0.0f;

        // each thread stages codes k0+tid and k0+tid+256 (8 c's per chunk)
        const float* e0p = emb + (size_t)(k0 + tid) * CDIM;
        const float* e1p = e0p + 256 * CDIM;
        float4 a0 = *(const float4*)(e0p);
        float4 b0 = *(const float4*)(e0p + 4);
        float4 a1 = *(const float4*)(e1p);
        float4 b1 = *(const float4*)(e1p + 4);
        float ee0 = 0.0f, ee1 = 0.0f;

        for (int c0 = 0; c0 < CDIM; c0 += 8) {
            __syncthreads();   // previous chunk's reads done
            et[0 * 512 + ph0] = a0.x; et[1 * 512 + ph0] = a0.y;
            et[2 * 512 + ph0] = a0.z; et[3 * 512 + ph0] = a0.w;
            et[4 * 512 + ph0] = b0.x; et[5 * 512 + ph0] = b0.y;
            et[6 * 512 + ph0] = b0.z; et[7 * 512 + ph0] = b0.w;
            et[0 * 512 + ph1] = a1.x; et[1 * 512 + ph1] = a1.y;
            et[2 * 512 + ph1] = a1.z; et[3 * 512 + ph1] = a1.w;
            et[4 * 512 + ph1] = b1.x; et[5 * 512 + ph1] = b1.y;
            et[6 * 512 + ph1] = b1.z; et[7 * 512 + ph1] = b1.w;
            // fused e-norm accumulation (c-ascending order)
            ee0 = fmaf(a0.x, a0.x, ee0); ee0 = fmaf(a0.y, a0.y, ee0);
            ee0 = fmaf(a0.z, a0.z, ee0); ee0 = fmaf(a0.w, a0.w, ee0);
            ee0 = fmaf(b0.x, b0.x, ee0); ee0 = fmaf(b0.y, b0.y, ee0);
            ee0 = fmaf(b0.z, b0.z, ee0); ee0 = fmaf(b0.w, b0.w, ee0);
            ee1 = fmaf(a1.x, a1.x, ee1); ee1 = fmaf(a1.y, a1.y, ee1);
            ee1 = fmaf(a1.z, a1.z, ee1); ee1 = fmaf(a1.w, a1.w, ee1);
            ee1 = fmaf(b1.x, b1.x, ee1); ee1 = fmaf(b1.y, b1.y, ee1);
            ee1 = fmaf(b1.z, b1.z, ee1); ee1 = fmaf(b1.w, b1.w, ee1);
            __syncthreads();
            // prefetch next chunk during compute
            if (c0 < CDIM - 8) {
                a0 = *(const float4*)(e0p + c0 + 8);
                b0 = *(const float4*)(e0p + c0 + 12);
                a1 = *(const float4*)(e1p + c0 + 8);
                b1 = *(const float4*)(e1p + c0 + 12);
            }
#pragma unroll
            for (int cc = 0; cc < 8; ++cc) {
                const float* zrow = &zt[(c0 + cc) * 64 + cx * 8];
                float4 z0 = *(const float4*)(zrow);
                float4 z1 = *(const float4*)(zrow + 4);
                const float* erow = &et[cc * 512];
                float4 e0 = *(const float4*)(erow + rb0);
                float4 e1 = *(const float4*)(erow + rb1);
                float4 e2 = *(const float4*)(erow + rb2);
                float4 e3 = *(const float4*)(erow + rb3);
                float zv[8] = {z0.x, z0.y, z0.z, z0.w, z1.x, z1.y, z1.z, z1.w};
                float ev[16] = {e0.x, e0.y, e0.z, e0.w, e1.x, e1.y, e1.z, e1.w,
                                e2.x, e2.y, e2.z, e2.w, e3.x, e3.y, e3.z, e3.w};
#pragma unroll
                for (int i = 0; i < 16; ++i)
#pragma unroll
                    for (int j = 0; j < 8; ++j)
                        acc[i][j] = fmaf(ev[i], zv[j], acc[i][j]);
            }
        }

        // ---- exchange e-norms through et overlay ----
        __syncthreads();
        et[tid] = ee0;          // code k0+tid        -> kk = tid
        et[256 + tid] = ee1;    // code k0+256+tid    -> kk = 256+tid
        __syncthreads();
        float en[16];
        *(float4*)&en[0]  = *(const float4*)&et[ky * 16];
        *(float4*)&en[4]  = *(const float4*)&et[ky * 16 + 4];
        *(float4*)&en[8]  = *(const float4*)&et[ky * 16 + 8];
        *(float4*)&en[12] = *(const float4*)&et[ky * 16 + 12];

        // tile epilogue: replicate np's d = fp32(zz + ee) - 2*M quantization
#pragma unroll
        for (int i = 0; i < 16; ++i) {
            const int k = k0 + ky * 16 + i;
#pragma unroll
            for (int j = 0; j < 8; ++j) {
                float tt = zzv[j] + en[i];
                float d = tt - 2.0f * acc[i][j];
                if (d < bs[j]) { bs[j] = d; bi[j] = k; }  // ascending k: ties keep lowest
            }
        }
        // next tile's first __syncthreads protects the et overlay
    }

    // ---- merge across ky within wave (lane bits 3..5), tie-break low index ----
#pragma unroll
    for (int m = 8; m <= 32; m <<= 1) {
#pragma unroll
        for (int j = 0; j < 8; ++j) {
            float s2 = __shfl_xor(bs[j], m, 64);
            int   i2 = __shfl_xor(bi[j], m, 64);
            if (s2 < bs[j] || (s2 == bs[j] && i2 < bi[j])) { bs[j] = s2; bi[j] = i2; }
        }
    }
    __syncthreads();                        // everyone done reading et overlay
    float* red_s = et;                      // [4][64]
    int*   red_i = (int*)&et[256];          // [4][64]
    int*   bidx  = (int*)&et[512];          // [64]
    {
        int w = tid >> 6, lane = tid & 63;
        if (lane < 8) {
#pragma unroll
            for (int j = 0; j < 8; ++j) {
                red_s[w * 64 + lane * 8 + j] = bs[j];
                red_i[w * 64 + lane * 8 + j] = bi[j];
            }
        }
    }
    __syncthreads();
    if (tid < 64) {
        float s = red_s[tid];
        int ki = red_i[tid];
#pragma unroll
        for (int w2 = 1; w2 < 4; ++w2) {
            float s2 = red_s[w2 * 64 + tid];
            int k2 = red_i[w2 * 64 + tid];
            if (s2 < s || (s2 == s && k2 < ki)) { s = s2; ki = k2; }
        }
        out[IDX_OFF + n0 + tid] = (float)ki;
        atomicAdd(&counts[ki], 1.0f);
        bidx[tid] = ki;
    }
    __syncthreads();

    // ---- gather z_q, STE output zp + (q - zp), loss partial ----
    float ls = 0.0f;
    float* outz = out + (size_t)b * CDIM * SPAT + sp0;
    for (int i = tid; i < CDIM * 16; i += 256) {
        int c = i >> 4, seg = i & 15;
        float4 zp = *(const float4*)&zt[c * 64 + seg * 4];
        int kk0 = bidx[seg * 4 + 0];
        int kk1b = bidx[seg * 4 + 1];
        int kk2 = bidx[seg * 4 + 2];
        int kk3 = bidx[seg * 4 + 3];
        float q0 = emb[(size_t)kk0 * CDIM + c];
        float q1 = emb[(size_t)kk1b * CDIM + c];
        float q2 = emb[(size_t)kk2 * CDIM + c];
        float q3 = emb[(size_t)kk3 * CDIM + c];
        float d0 = q0 - zp.x, d1 = q1 - zp.y, d2 = q2 - zp.z, d3 = q3 - zp.w;
        float4 o;
        o.x = zp.x + d0; o.y = zp.y + d1; o.z = zp.z + d2; o.w = zp.w + d3;
        ls = fmaf(d0, d0, ls); ls = fmaf(d1, d1, ls);
        ls = fmaf(d2, d2, ls); ls = fmaf(d3, d3, ls);
        *(float4*)(outz + (size_t)c * SPAT + seg * 4) = o;
    }
#pragma unroll
    for (int m = 32; m > 0; m >>= 1) ls += __shfl_xor(ls, m, 64);
    if ((tid & 63) == 0) atomicAdd(losssum, ls);
}

// ---------------------------------------------------------------------------
// loss + perplexity
// ---------------------------------------------------------------------------
__global__ __launch_bounds__(256) void vq_finalize(const float* __restrict__ counts,
                                                   const float* __restrict__ losssum,
                                                   float* __restrict__ out) {
    __shared__ float red[256];
    int tid = threadIdx.x;
    float s = 0.0f;
    for (int k = tid; k < KCODE; k += 256) {
        float em = counts[k] * (1.0f / 32768.0f);
        s += em * logf(em + 1e-10f);
    }
    red[tid] = s;
    __syncthreads();
    for (int off = 128; off > 0; off >>= 1) {
        if (tid < off) red[tid] += red[tid + off];
        __syncthreads();
    }
    if (tid == 0) {
        float m = losssum[0] * (1.0f / 8388608.0f);
        out[LOSS_OFF] = m + 0.25f * m;
        out[PERP_OFF] = expf(-red[0]);
    }
}

extern "C" void kernel_launch(void* const* d_in, const int* in_sizes, int n_in,
                              void* d_out, int out_size, void* d_ws, size_t ws_size,
                              hipStream_t stream) {
    const float* z = (const float*)d_in[0];
    const float* emb = (const float*)d_in[1];
    float* out = (float*)d_out;
    float* counts = (float*)d_ws;       // 1024 floats
    float* losssum = counts + KCODE;    // 1 float

    hipMemsetAsync(d_ws, 0, (KCODE + 1) * sizeof(float), stream);
    vq_main<<<512, 256, 0, stream>>>(z, emb, counts, losssum, out);
    vq_finalize<<<1, 256, 0, stream>>>(counts, losssum, out);
}

// Round 3
// 197.028 us; speedup vs baseline: 5.3499x; 5.3499x over previous
//
#include <hip/hip_runtime.h>
#include <cstddef>
#include <cstdint>

// z: (8, 256, 16,16,16) fp32; embedding: (1024, 256) fp32
#define CDIM 256
#define SPAT 4096
#define KCODE 1024

#define LOSS_OFF 8388608
#define PERP_OFF 8388609
#define IDX_OFF  8388610

typedef __bf16 bf16x8 __attribute__((ext_vector_type(8)));
typedef float floatx16 __attribute__((ext_vector_type(16)));
typedef unsigned short ushort8 __attribute__((ext_vector_type(8)));

__device__ __forceinline__ unsigned short f2bf_rne(float f) {
    union { float f; uint32_t u; } c; c.f = f;
    uint32_t u = c.u;
    return (unsigned short)((u + 0x7fffu + ((u >> 16) & 1u)) >> 16);
}
__device__ __forceinline__ float bf2f(unsigned short h) {
    union { float f; uint32_t u; } c; c.u = ((uint32_t)h) << 16;
    return c.f;
}

// ---------------------------------------------------------------------------
// Prep: split embedding into bf16 hi/lo tables (exact: e = hi + lo + ~2^-18)
// and compute enorm (fp32, same wave-reduce as the R1-passing kernel).
// grid 256 x 256: block handles 4 codes (one per wave).
// ---------------------------------------------------------------------------
__global__ __launch_bounds__(256) void vq_prep(const float* __restrict__ emb,
                                               unsigned short* __restrict__ eh,
                                               unsigned short* __restrict__ el,
                                               float* __restrict__ enorm) {
    int tid = threadIdx.x;
    int w = tid >> 6, lane = tid & 63;
    int k = blockIdx.x * 4 + w;
    const float* row = emb + (size_t)k * CDIM;
    // enorm: exact R1 structure (4 strided fmaf + butterfly)
    float s = 0.0f;
#pragma unroll
    for (int i = 0; i < 4; ++i) {
        float v = row[lane + 64 * i];
        s = fmaf(v, v, s);
    }
#pragma unroll
    for (int m = 32; m > 0; m >>= 1) s += __shfl_xor(s, m, 64);
    if (lane == 0) enorm[k] = s;
    // split: each lane converts 4 consecutive elements
    float4 v4 = *(const float4*)(row + lane * 4);
    unsigned short h0 = f2bf_rne(v4.x), h1 = f2bf_rne(v4.y),
                   h2 = f2bf_rne(v4.z), h3 = f2bf_rne(v4.w);
    ushort4 hv = make_ushort4(h0, h1, h2, h3);
    ushort4 lv = make_ushort4(f2bf_rne(v4.x - bf2f(h0)), f2bf_rne(v4.y - bf2f(h1)),
                              f2bf_rne(v4.z - bf2f(h2)), f2bf_rne(v4.w - bf2f(h3)));
    *(ushort4*)(eh + (size_t)k * CDIM + lane * 4) = hv;
    *(ushort4*)(el + (size_t)k * CDIM + lane * 4) = lv;
}

// ---------------------------------------------------------------------------
// Main: bf16x3 MFMA distance GEMM + argmin + gather + loss + counts
// grid 256 blocks x 256 threads, 128 cols/block, wave w owns cols [32w,32w+32)
// GEMM: D[code m][col n] via mfma_f32_32x32x16_bf16, A = e (LDS staged,
// 32-code stages, XOR-swizzled), B = z (held in registers: 16 kc x hi/lo).
// d = fp32(zz+ee) - 2*M  replicates np's rounding structure exactly.
// ---------------------------------------------------------------------------
__global__ __launch_bounds__(256, 1) void vq_main(const float* __restrict__ z,
                                                  const float* __restrict__ emb,
                                                  const unsigned short* __restrict__ ehg,
                                                  const unsigned short* __restrict__ elg,
                                                  const float* __restrict__ enorm,
                                                  float* __restrict__ counts,
                                                  float* __restrict__ losssum,
                                                  float* __restrict__ out) {
    __shared__ float smem[16384];    // 64 KB: fp32 z half-tile, later e-stage
    __shared__ float zzs[128];
    __shared__ float ens[32];
    __shared__ int bidxs[128];

    const int tid = threadIdx.x;
    const int wave = tid >> 6;
    const int lane = tid & 63;
    const int n0 = blockIdx.x * 128;       // first global column
    const int b = n0 >> 12;
    const int sp0 = n0 & 4095;
    const float* zb = z + (size_t)b * CDIM * SPAT + sp0;

    const int m_ = lane & 31;              // MFMA row (code within tile) / col
    const int g = lane >> 5;               // k-half selector

    // z fragments in registers: 16 kc-steps x {hi,lo}
    ushort8 zh_u[16], zl_u[16];

    // ---- phase 1: two 64-col halves: stage fp32, zz (R1-exact), extract ----
    for (int h = 0; h < 2; ++h) {
        for (int i = tid; i < CDIM * 16; i += 256) {
            int c = i >> 4, seg = i & 15;
            float4 v = *(const float4*)(zb + (size_t)c * SPAT + h * 64 + seg * 4);
            *(float4*)&smem[c * 64 + seg * 4] = v;
        }
        __syncthreads();
        if (tid < 64) {   // zz: sequential c-ascending fmaf (R1-identical)
            float s = 0.0f;
            for (int c = 0; c < CDIM; ++c) {
                float v = smem[c * 64 + tid];
                s = fmaf(v, v, s);
            }
            zzs[h * 64 + tid] = s;
        }
        if ((wave >> 1) == h) {   // extract this wave's B-fragments
            int lcol = (wave & 1) * 32 + m_;
#pragma unroll
            for (int kc = 0; kc < 16; ++kc) {
#pragma unroll
                for (int j = 0; j < 8; ++j) {
                    int c = kc * 16 + g * 8 + j;
                    float v = smem[c * 64 + lcol];
                    unsigned short hb = f2bf_rne(v);
                    zh_u[kc][j] = hb;
                    zl_u[kc][j] = f2bf_rne(v - bf2f(hb));
                }
            }
        }
        __syncthreads();
    }

    const float zzv = zzs[wave * 32 + m_];
    unsigned short* ehs = (unsigned short*)smem;          // 32x256 ushort, 16 KB
    unsigned short* els = (unsigned short*)(smem + 4096); // next 16 KB

    float bs = 3.4e38f;
    int bi = 0;

    // ---- main loop: 32 stages of 32 codes ----
    for (int s = 0; s < 32; ++s) {
        __syncthreads();   // previous stage's reads done / phase-1 reads done
        // stage eh/el: 1024 16B-chunks per split; thread -> 4 consecutive
        {
            const ushort8* src_h = (const ushort8*)(ehg + (size_t)s * 32 * CDIM);
            const ushort8* src_l = (const ushort8*)(elg + (size_t)s * 32 * CDIM);
#pragma unroll
            for (int q = 0; q < 4; ++q) {
                int cid = tid * 4 + q;          // = code*32 + kb
                int code = cid >> 5, kb = cid & 31;
                int kbs = kb ^ (code & 31);     // XOR swizzle
                *(ushort8*)&ehs[code * 256 + kbs * 8] = src_h[cid];
                *(ushort8*)&els[code * 256 + kbs * 8] = src_l[cid];
            }
            if (tid < 32) ens[tid] = enorm[s * 32 + tid];
        }
        __syncthreads();

        floatx16 acc = {0.0f, 0.0f, 0.0f, 0.0f, 0.0f, 0.0f, 0.0f, 0.0f,
                        0.0f, 0.0f, 0.0f, 0.0f, 0.0f, 0.0f, 0.0f, 0.0f};
#pragma unroll
        for (int kc = 0; kc < 16; ++kc) {
            int kb0 = kc * 2 + g;
            int off = m_ * 256 + ((kb0 ^ (m_ & 31)) << 3);
            bf16x8 a_eh = *(const bf16x8*)&ehs[off];
            bf16x8 a_el = *(const bf16x8*)&els[off];
            bf16x8 b_zh = __builtin_bit_cast(bf16x8, zh_u[kc]);
            bf16x8 b_zl = __builtin_bit_cast(bf16x8, zl_u[kc]);
            acc = __builtin_amdgcn_mfma_f32_32x32x16_bf16(a_eh, b_zh, acc, 0, 0, 0);
            acc = __builtin_amdgcn_mfma_f32_32x32x16_bf16(a_el, b_zh, acc, 0, 0, 0);
            acc = __builtin_amdgcn_mfma_f32_32x32x16_bf16(a_eh, b_zl, acc, 0, 0, 0);
        }

        // epilogue: ascending code order per lane; strict < keeps lowest idx
#pragma unroll
        for (int reg = 0; reg < 16; ++reg) {
            int mm = (reg & 3) + 8 * (reg >> 2) + 4 * g;
            int code = s * 32 + mm;
            float tt = zzv + ens[mm];           // rounded like np (zz+ee)
            float d = tt - 2.0f * acc[reg];
            if (d < bs) { bs = d; bi = code; }
        }
    }

    // ---- merge the two k-half lanes (disjoint code subsets), tie -> low ----
    {
        float s2 = __shfl_xor(bs, 32, 64);
        int i2 = __shfl_xor(bi, 32, 64);
        if (s2 < bs || (s2 == bs && i2 < bi)) { bs = s2; bi = i2; }
    }
    if (lane < 32) {
        int col = wave * 32 + lane;
        bidxs[col] = bi;
        out[IDX_OFF + n0 + col] = (float)bi;
        atomicAdd(&counts[bi], 1.0f);
    }
    __syncthreads();

    // ---- gather z_q, STE output zp + (q - zp), loss partial (R1-exact math) ----
    float ls = 0.0f;
    float* outz = out + (size_t)b * CDIM * SPAT + sp0;
    for (int i = tid; i < CDIM * 32; i += 256) {
        int c = i >> 5, seg = i & 31;
        float4 zp = *(const float4*)(zb + (size_t)c * SPAT + seg * 4);
        int k0 = bidxs[seg * 4 + 0];
        int k1 = bidxs[seg * 4 + 1];
        int k2 = bidxs[seg * 4 + 2];
        int k3 = bidxs[seg * 4 + 3];
        float q0 = emb[(size_t)k0 * CDIM + c];
        float q1 = emb[(size_t)k1 * CDIM + c];
        float q2 = emb[(size_t)k2 * CDIM + c];
        float q3 = emb[(size_t)k3 * CDIM + c];
        float d0 = q0 - zp.x, d1 = q1 - zp.y, d2 = q2 - zp.z, d3 = q3 - zp.w;
        float4 o;
        o.x = zp.x + d0; o.y = zp.y + d1; o.z = zp.z + d2; o.w = zp.w + d3;
        ls = fmaf(d0, d0, ls); ls = fmaf(d1, d1, ls);
        ls = fmaf(d2, d2, ls); ls = fmaf(d3, d3, ls);
        *(float4*)(outz + (size_t)c * SPAT + seg * 4) = o;
    }
#pragma unroll
    for (int m = 32; m > 0; m >>= 1) ls += __shfl_xor(ls, m, 64);
    if (lane == 0) atomicAdd(losssum, ls);
}

// ---------------------------------------------------------------------------
// loss + perplexity
// ---------------------------------------------------------------------------
__global__ __launch_bounds__(256) void vq_finalize(const float* __restrict__ counts,
                                                   const float* __restrict__ losssum,
                                                   float* __restrict__ out) {
    __shared__ float red[256];
    int tid = threadIdx.x;
    float s = 0.0f;
    for (int k = tid; k < KCODE; k += 256) {
        float em = counts[k] * (1.0f / 32768.0f);
        s += em * logf(em + 1e-10f);
    }
    red[tid] = s;
    __syncthreads();
    for (int off = 128; off > 0; off >>= 1) {
        if (tid < off) red[tid] += red[tid + off];
        __syncthreads();
    }
    if (tid == 0) {
        float m = losssum[0] * (1.0f / 8388608.0f);
        out[LOSS_OFF] = m + 0.25f * m;
        out[PERP_OFF] = expf(-red[0]);
    }
}

extern "C" void kernel_launch(void* const* d_in, const int* in_sizes, int n_in,
                              void* d_out, int out_size, void* d_ws, size_t ws_size,
                              hipStream_t stream) {
    const float* z = (const float*)d_in[0];
    const float* emb = (const float*)d_in[1];
    float* out = (float*)d_out;
    // workspace layout
    unsigned short* eh = (unsigned short*)d_ws;              // 1024*256 ushort
    unsigned short* el = eh + (size_t)KCODE * CDIM;          // 1024*256 ushort
    float* enorm = (float*)(el + (size_t)KCODE * CDIM);      // 1024 f
    float* counts = enorm + KCODE;                           // 1024 f
    float* losssum = counts + KCODE;                         // 1 f

    hipMemsetAsync(counts, 0, (KCODE + 1) * sizeof(float), stream);
    vq_prep<<<256, 256, 0, stream>>>(emb, eh, el, enorm);
    vq_main<<<256, 256, 0, stream>>>(z, emb, eh, el, enorm, counts, losssum, out);
    vq_finalize<<<1, 256, 0, stream>>>(counts, losssum, out);
}